// Round 1
// baseline (656.509 us; speedup 1.0000x reference)
//
#include <hip/hip_runtime.h>
#include <math.h>

#define N_SIMP 8192
#define K_FILT 8
#define BATCH  64
#define FEAT   128

// ---------------------------------------------------------------------------
// Kernel Z: zero the workspace accumulators (wL: 65536 floats, out_acc: 65536)
// ---------------------------------------------------------------------------
__global__ void zero_ws_kernel(float* __restrict__ p, int n) {
    int i = blockIdx.x * blockDim.x + threadIdx.x;
    if (i < n) p[i] = 0.0f;
}

// ---------------------------------------------------------------------------
// Kernel A: wL[k][n] += sum_{m in chunk} W[k][m] * L[m][n]
// grid = 8 n-tiles (1024 wide) x 64 m-chunks (128 rows) = 512 blocks, 256 thr
// L read fully coalesced float4 (16B/lane). W chunk staged in LDS (broadcast).
// ---------------------------------------------------------------------------
__global__ __launch_bounds__(256) void wl_kernel(const float* __restrict__ W,
                                                 const float* __restrict__ L,
                                                 float* __restrict__ wL) {
    const int ntile = blockIdx.x & 7;   // 8 tiles of 1024 columns
    const int mc    = blockIdx.x >> 3;  // 64 chunks of 128 rows
    const int n0    = ntile * 1024;
    const int m0    = mc * 128;

    __shared__ float Ws[K_FILT][128];   // 4 KB
    for (int idx = threadIdx.x; idx < K_FILT * 128; idx += 256) {
        int k = idx >> 7, j = idx & 127;
        Ws[k][j] = W[k * N_SIMP + m0 + j];
    }
    __syncthreads();

    const int n = n0 + threadIdx.x * 4;
    float4 acc[K_FILT];
#pragma unroll
    for (int k = 0; k < K_FILT; k++) acc[k] = make_float4(0.f, 0.f, 0.f, 0.f);

    const float* Lp = L + (size_t)m0 * N_SIMP + n;
    for (int j = 0; j < 128; j++) {
        float4 lv = *(const float4*)Lp;
        Lp += N_SIMP;
#pragma unroll
        for (int k = 0; k < K_FILT; k++) {
            float w = Ws[k][j];
            acc[k].x += w * lv.x;
            acc[k].y += w * lv.y;
            acc[k].z += w * lv.z;
            acc[k].w += w * lv.w;
        }
    }

#pragma unroll
    for (int k = 0; k < K_FILT; k++) {
        float* dst = &wL[k * N_SIMP + n];
        atomicAdd(dst + 0, acc[k].x);
        atomicAdd(dst + 1, acc[k].y);
        atomicAdd(dst + 2, acc[k].z);
        atomicAdd(dst + 3, acc[k].w);
    }
}

// ---------------------------------------------------------------------------
// Kernel B: out_acc[k][b][f] += sum_{n in chunk} wL[k][n] * x[b][n][f]
// grid = 64 b x 64 n-chunks (128 n each) = 4096 blocks, 64 threads (1 wave).
// lane = (nl:1bit)(f4:5bits): 32 lanes cover F=128 via float4, 2 n-rows/iter.
// Each x element reused for all 8 k in registers. shfl_xor(32) folds nl.
// ---------------------------------------------------------------------------
__global__ __launch_bounds__(64) void conv_kernel(const float* __restrict__ wL,
                                                  const float* __restrict__ x,
                                                  float* __restrict__ out_acc) {
    const int nc   = blockIdx.x & 63;   // 64 chunks of 128 n
    const int b    = blockIdx.x >> 6;
    const int n0   = nc * 128;
    const int lane = threadIdx.x;
    const int f0   = (lane & 31) * 4;
    const int nl   = lane >> 5;         // 0 or 1

    __shared__ float wls[K_FILT][128];  // 4 KB
    for (int idx = lane; idx < K_FILT * 128; idx += 64) {
        int k = idx >> 7, j = idx & 127;
        wls[k][j] = wL[k * N_SIMP + n0 + j];
    }
    __syncthreads();

    float4 acc[K_FILT];
#pragma unroll
    for (int k = 0; k < K_FILT; k++) acc[k] = make_float4(0.f, 0.f, 0.f, 0.f);

    const float* xp = x + (size_t)b * N_SIMP * FEAT + (size_t)(n0 + nl) * FEAT + f0;
    for (int jj = 0; jj < 64; jj++) {
        int j = jj * 2 + nl;
        float4 xv = *(const float4*)xp;
        xp += 2 * FEAT;
#pragma unroll
        for (int k = 0; k < K_FILT; k++) {
            float w = wls[k][j];
            acc[k].x += w * xv.x;
            acc[k].y += w * xv.y;
            acc[k].z += w * xv.z;
            acc[k].w += w * xv.w;
        }
    }

    // fold the nl=0 / nl=1 halves of the wave
#pragma unroll
    for (int k = 0; k < K_FILT; k++) {
        acc[k].x += __shfl_xor(acc[k].x, 32);
        acc[k].y += __shfl_xor(acc[k].y, 32);
        acc[k].z += __shfl_xor(acc[k].z, 32);
        acc[k].w += __shfl_xor(acc[k].w, 32);
    }

    if (nl == 0) {
#pragma unroll
        for (int k = 0; k < K_FILT; k++) {
            float* dst = &out_acc[((size_t)k * BATCH + b) * FEAT + f0];
            atomicAdd(dst + 0, acc[k].x);
            atomicAdd(dst + 1, acc[k].y);
            atomicAdd(dst + 2, acc[k].z);
            atomicAdd(dst + 3, acc[k].w);
        }
    }
}

// ---------------------------------------------------------------------------
// Kernel C: out = tanh(out_acc)
// ---------------------------------------------------------------------------
__global__ void tanh_kernel(const float* __restrict__ acc, float* __restrict__ out) {
    int i = blockIdx.x * blockDim.x + threadIdx.x;
    if (i < K_FILT * BATCH * FEAT) out[i] = tanhf(acc[i]);
}

extern "C" void kernel_launch(void* const* d_in, const int* in_sizes, int n_in,
                              void* d_out, int out_size, void* d_ws, size_t ws_size,
                              hipStream_t stream) {
    const float* x = (const float*)d_in[0];  // [64, 8192, 128]
    const float* L = (const float*)d_in[1];  // [8192, 8192]
    const float* W = (const float*)d_in[2];  // [8, 8192]
    float* out = (float*)d_out;              // [8, 64, 128]

    float* wL      = (float*)d_ws;                    // 65536 floats
    float* out_acc = wL + (size_t)K_FILT * N_SIMP;    // 65536 floats

    const int n_zero = K_FILT * N_SIMP + K_FILT * BATCH * FEAT;  // 131072
    zero_ws_kernel<<<(n_zero + 255) / 256, 256, 0, stream>>>(wL, n_zero);

    wl_kernel<<<512, 256, 0, stream>>>(W, L, wL);

    conv_kernel<<<BATCH * 64, 64, 0, stream>>>(wL, x, out_acc);

    tanh_kernel<<<(K_FILT * BATCH * FEAT + 255) / 256, 256, 0, stream>>>(out_acc, out);
}

// Round 2
// 514.267 us; speedup vs baseline: 1.2766x; 1.2766x over previous
//
#include <hip/hip_runtime.h>
#include <math.h>

#define N_SIMP 8192
#define K_FILT 8
#define BATCH  64
#define FEAT   128
#define MCHUNK 64   // m-chunks for wL partials
#define NCHUNK 64   // n-chunks for conv partials

// ============================================================================
// FAST PATH (two-stage, no atomics) — needs ws >= 16 MB partials + 256 KB wL
// ============================================================================

// ---------------------------------------------------------------------------
// wl_partial: pL[mc][k][n] = sum_{m in chunk mc} W[k][m] * L[m][n]
// grid = 8 n-tiles (1024 cols) x 64 m-chunks (128 rows) = 512 blocks, 256 thr
// m-loop unrolled x4: 4 independent float4 loads in flight per wave.
// ---------------------------------------------------------------------------
__global__ __launch_bounds__(256) void wl_partial_kernel(const float* __restrict__ W,
                                                         const float* __restrict__ L,
                                                         float* __restrict__ pL) {
    const int ntile = blockIdx.x & 7;
    const int mc    = blockIdx.x >> 3;
    const int n0    = ntile * 1024;
    const int m0    = mc * 128;

    __shared__ float Ws[K_FILT][128];
    for (int idx = threadIdx.x; idx < K_FILT * 128; idx += 256) {
        int k = idx >> 7, j = idx & 127;
        Ws[k][j] = W[k * N_SIMP + m0 + j];
    }
    __syncthreads();

    const int n = n0 + threadIdx.x * 4;
    float4 acc[K_FILT];
#pragma unroll
    for (int k = 0; k < K_FILT; k++) acc[k] = make_float4(0.f, 0.f, 0.f, 0.f);

    const float* Lp = L + (size_t)m0 * N_SIMP + n;
    for (int j0 = 0; j0 < 128; j0 += 4) {
        float4 l0 = *(const float4*)(Lp);
        float4 l1 = *(const float4*)(Lp + N_SIMP);
        float4 l2 = *(const float4*)(Lp + 2 * N_SIMP);
        float4 l3 = *(const float4*)(Lp + 3 * N_SIMP);
        Lp += 4 * N_SIMP;
#pragma unroll
        for (int k = 0; k < K_FILT; k++) {
            float w0 = Ws[k][j0], w1 = Ws[k][j0 + 1], w2 = Ws[k][j0 + 2], w3 = Ws[k][j0 + 3];
            acc[k].x += w0 * l0.x; acc[k].y += w0 * l0.y; acc[k].z += w0 * l0.z; acc[k].w += w0 * l0.w;
            acc[k].x += w1 * l1.x; acc[k].y += w1 * l1.y; acc[k].z += w1 * l1.z; acc[k].w += w1 * l1.w;
            acc[k].x += w2 * l2.x; acc[k].y += w2 * l2.y; acc[k].z += w2 * l2.z; acc[k].w += w2 * l2.w;
            acc[k].x += w3 * l3.x; acc[k].y += w3 * l3.y; acc[k].z += w3 * l3.z; acc[k].w += w3 * l3.w;
        }
    }

#pragma unroll
    for (int k = 0; k < K_FILT; k++)
        *(float4*)&pL[(size_t)(mc * K_FILT + k) * N_SIMP + n] = acc[k];
}

// ---------------------------------------------------------------------------
// wl_reduce: wL[k][n] = sum_mc pL[mc][k][n].  16384 threads, float4 each.
// ---------------------------------------------------------------------------
__global__ __launch_bounds__(256) void wl_reduce_kernel(const float* __restrict__ pL,
                                                        float* __restrict__ wL) {
    const int i4 = (blockIdx.x * 256 + threadIdx.x) * 4;  // 0..65532
    float4 s = make_float4(0.f, 0.f, 0.f, 0.f);
#pragma unroll 4
    for (int mc = 0; mc < MCHUNK; mc++) {
        float4 v = *(const float4*)&pL[(size_t)mc * (K_FILT * N_SIMP) + i4];
        s.x += v.x; s.y += v.y; s.z += v.z; s.w += v.w;
    }
    *(float4*)&wL[i4] = s;
}

// ---------------------------------------------------------------------------
// conv_partial: pO[nc][k][b][f] = sum_{n in chunk nc} wL[k][n] * x[b][n][f]
// grid = 64 b x 64 n-chunks (128 n) = 4096 blocks, 64 threads (1 wave).
// lanes 0-31: rows j even (f via float4); lanes 32-63: rows j odd.
// n-loop unrolled x4 (8 rows/iter): 4 independent float4 loads in flight.
// ---------------------------------------------------------------------------
__global__ __launch_bounds__(64) void conv_partial_kernel(const float* __restrict__ wL,
                                                          const float* __restrict__ x,
                                                          float* __restrict__ pO) {
    const int nc   = blockIdx.x & 63;
    const int b    = blockIdx.x >> 6;
    const int n0   = nc * 128;
    const int lane = threadIdx.x;
    const int f0   = (lane & 31) * 4;
    const int nl   = lane >> 5;

    __shared__ float wls[K_FILT][128];
    for (int idx = lane; idx < K_FILT * 128; idx += 64) {
        int k = idx >> 7, j = idx & 127;
        wls[k][j] = wL[k * N_SIMP + n0 + j];
    }
    __syncthreads();

    float4 acc[K_FILT];
#pragma unroll
    for (int k = 0; k < K_FILT; k++) acc[k] = make_float4(0.f, 0.f, 0.f, 0.f);

    const float* xp = x + (size_t)b * N_SIMP * FEAT + (size_t)(n0 + nl) * FEAT + f0;
    for (int j0 = 0; j0 < 128; j0 += 8) {
        float4 x0 = *(const float4*)(xp);
        float4 x1 = *(const float4*)(xp + 2 * FEAT);
        float4 x2 = *(const float4*)(xp + 4 * FEAT);
        float4 x3 = *(const float4*)(xp + 6 * FEAT);
        xp += 8 * FEAT;
#pragma unroll
        for (int k = 0; k < K_FILT; k++) {
            float w0 = wls[k][j0 + 0 + nl];
            float w1 = wls[k][j0 + 2 + nl];
            float w2 = wls[k][j0 + 4 + nl];
            float w3 = wls[k][j0 + 6 + nl];
            acc[k].x += w0 * x0.x; acc[k].y += w0 * x0.y; acc[k].z += w0 * x0.z; acc[k].w += w0 * x0.w;
            acc[k].x += w1 * x1.x; acc[k].y += w1 * x1.y; acc[k].z += w1 * x1.z; acc[k].w += w1 * x1.w;
            acc[k].x += w2 * x2.x; acc[k].y += w2 * x2.y; acc[k].z += w2 * x2.z; acc[k].w += w2 * x2.w;
            acc[k].x += w3 * x3.x; acc[k].y += w3 * x3.y; acc[k].z += w3 * x3.z; acc[k].w += w3 * x3.w;
        }
    }

#pragma unroll
    for (int k = 0; k < K_FILT; k++) {
        acc[k].x += __shfl_xor(acc[k].x, 32);
        acc[k].y += __shfl_xor(acc[k].y, 32);
        acc[k].z += __shfl_xor(acc[k].z, 32);
        acc[k].w += __shfl_xor(acc[k].w, 32);
    }

    if (nl == 0) {
#pragma unroll
        for (int k = 0; k < K_FILT; k++)
            *(float4*)&pO[((size_t)(nc * K_FILT + k) * BATCH + b) * FEAT + f0] = acc[k];
    }
}

// ---------------------------------------------------------------------------
// conv_reduce: out[k][b][f] = tanh(sum_nc pO[nc][k][b][f]).  16384 thr, float4.
// ---------------------------------------------------------------------------
__global__ __launch_bounds__(256) void conv_reduce_kernel(const float* __restrict__ pO,
                                                          float* __restrict__ out) {
    const int i4 = (blockIdx.x * 256 + threadIdx.x) * 4;
    float4 s = make_float4(0.f, 0.f, 0.f, 0.f);
#pragma unroll 4
    for (int nc = 0; nc < NCHUNK; nc++) {
        float4 v = *(const float4*)&pO[(size_t)nc * (K_FILT * BATCH * FEAT) + i4];
        s.x += v.x; s.y += v.y; s.z += v.z; s.w += v.w;
    }
    float4 r;
    r.x = tanhf(s.x); r.y = tanhf(s.y); r.z = tanhf(s.z); r.w = tanhf(s.w);
    *(float4*)&out[i4] = r;
}

// ============================================================================
// FALLBACK PATH (round-1 atomics) — used only if ws is too small
// ============================================================================
__global__ void zero_ws_kernel(float* __restrict__ p, int n) {
    int i = blockIdx.x * blockDim.x + threadIdx.x;
    if (i < n) p[i] = 0.0f;
}

__global__ __launch_bounds__(256) void wl_atomic_kernel(const float* __restrict__ W,
                                                        const float* __restrict__ L,
                                                        float* __restrict__ wL) {
    const int ntile = blockIdx.x & 7;
    const int mc    = blockIdx.x >> 3;
    const int n0    = ntile * 1024;
    const int m0    = mc * 128;
    __shared__ float Ws[K_FILT][128];
    for (int idx = threadIdx.x; idx < K_FILT * 128; idx += 256) {
        int k = idx >> 7, j = idx & 127;
        Ws[k][j] = W[k * N_SIMP + m0 + j];
    }
    __syncthreads();
    const int n = n0 + threadIdx.x * 4;
    float4 acc[K_FILT];
#pragma unroll
    for (int k = 0; k < K_FILT; k++) acc[k] = make_float4(0.f, 0.f, 0.f, 0.f);
    const float* Lp = L + (size_t)m0 * N_SIMP + n;
    for (int j = 0; j < 128; j++) {
        float4 lv = *(const float4*)Lp;
        Lp += N_SIMP;
#pragma unroll
        for (int k = 0; k < K_FILT; k++) {
            float w = Ws[k][j];
            acc[k].x += w * lv.x; acc[k].y += w * lv.y; acc[k].z += w * lv.z; acc[k].w += w * lv.w;
        }
    }
#pragma unroll
    for (int k = 0; k < K_FILT; k++) {
        float* dst = &wL[k * N_SIMP + n];
        atomicAdd(dst + 0, acc[k].x); atomicAdd(dst + 1, acc[k].y);
        atomicAdd(dst + 2, acc[k].z); atomicAdd(dst + 3, acc[k].w);
    }
}

__global__ __launch_bounds__(64) void conv_atomic_kernel(const float* __restrict__ wL,
                                                         const float* __restrict__ x,
                                                         float* __restrict__ out_acc) {
    const int nc   = blockIdx.x & 63;
    const int b    = blockIdx.x >> 6;
    const int n0   = nc * 128;
    const int lane = threadIdx.x;
    const int f0   = (lane & 31) * 4;
    const int nl   = lane >> 5;
    __shared__ float wls[K_FILT][128];
    for (int idx = lane; idx < K_FILT * 128; idx += 64) {
        int k = idx >> 7, j = idx & 127;
        wls[k][j] = wL[k * N_SIMP + n0 + j];
    }
    __syncthreads();
    float4 acc[K_FILT];
#pragma unroll
    for (int k = 0; k < K_FILT; k++) acc[k] = make_float4(0.f, 0.f, 0.f, 0.f);
    const float* xp = x + (size_t)b * N_SIMP * FEAT + (size_t)(n0 + nl) * FEAT + f0;
    for (int jj = 0; jj < 64; jj++) {
        int j = jj * 2 + nl;
        float4 xv = *(const float4*)xp;
        xp += 2 * FEAT;
#pragma unroll
        for (int k = 0; k < K_FILT; k++) {
            float w = wls[k][j];
            acc[k].x += w * xv.x; acc[k].y += w * xv.y; acc[k].z += w * xv.z; acc[k].w += w * xv.w;
        }
    }
#pragma unroll
    for (int k = 0; k < K_FILT; k++) {
        acc[k].x += __shfl_xor(acc[k].x, 32);
        acc[k].y += __shfl_xor(acc[k].y, 32);
        acc[k].z += __shfl_xor(acc[k].z, 32);
        acc[k].w += __shfl_xor(acc[k].w, 32);
    }
    if (nl == 0) {
#pragma unroll
        for (int k = 0; k < K_FILT; k++) {
            float* dst = &out_acc[((size_t)k * BATCH + b) * FEAT + f0];
            atomicAdd(dst + 0, acc[k].x); atomicAdd(dst + 1, acc[k].y);
            atomicAdd(dst + 2, acc[k].z); atomicAdd(dst + 3, acc[k].w);
        }
    }
}

__global__ void tanh_kernel(const float* __restrict__ acc, float* __restrict__ out) {
    int i = blockIdx.x * blockDim.x + threadIdx.x;
    if (i < K_FILT * BATCH * FEAT) out[i] = tanhf(acc[i]);
}

// ============================================================================
extern "C" void kernel_launch(void* const* d_in, const int* in_sizes, int n_in,
                              void* d_out, int out_size, void* d_ws, size_t ws_size,
                              hipStream_t stream) {
    const float* x = (const float*)d_in[0];  // [64, 8192, 128]
    const float* L = (const float*)d_in[1];  // [8192, 8192]
    const float* W = (const float*)d_in[2];  // [8, 8192]
    float* out = (float*)d_out;              // [8, 64, 128]

    const size_t partial_elems = (size_t)MCHUNK * K_FILT * N_SIMP;  // == NCHUNK*K*B*F = 4M floats
    const size_t need = (partial_elems + K_FILT * N_SIMP) * sizeof(float);  // 16 MB + 256 KB

    if (ws_size >= need) {
        float* partials = (float*)d_ws;                 // 16 MB (pL, then reused as pO)
        float* wL       = partials + partial_elems;     // 256 KB

        wl_partial_kernel<<<8 * MCHUNK, 256, 0, stream>>>(W, L, partials);
        wl_reduce_kernel<<<64, 256, 0, stream>>>(partials, wL);
        conv_partial_kernel<<<BATCH * NCHUNK, 64, 0, stream>>>(wL, x, partials);
        conv_reduce_kernel<<<64, 256, 0, stream>>>(partials, out);
    } else {
        float* wL      = (float*)d_ws;
        float* out_acc = wL + (size_t)K_FILT * N_SIMP;
        const int n_zero = K_FILT * N_SIMP + K_FILT * BATCH * FEAT;
        zero_ws_kernel<<<(n_zero + 255) / 256, 256, 0, stream>>>(wL, n_zero);
        wl_atomic_kernel<<<512, 256, 0, stream>>>(W, L, wL);
        conv_atomic_kernel<<<BATCH * 64, 64, 0, stream>>>(wL, x, out_acc);
        tanh_kernel<<<(K_FILT * BATCH * FEAT + 255) / 256, 256, 0, stream>>>(out_acc, out);
    }
}